// Round 1
// baseline (922.544 us; speedup 1.0000x reference)
//
#include <hip/hip_runtime.h>
#include <hip/hip_bf16.h>
#include <math.h>

// Problem constants
#define B_   512
#define NS_  2
#define S_   128
#define H_   768
#define DS_  384
#define NL_  40
#define H3_  (3*H_)      // 2304
#define TEMP_ 0.05f
#define ALPHA_ 0.15f
#define GAMMA_ 7.5f
#define EPS_ 1e-8f

// ---------------- helpers ----------------

__device__ __forceinline__ float block_reduce_sum(float v, float* sh) {
    int t = threadIdx.x;
    sh[t] = v; __syncthreads();
    for (int s = blockDim.x / 2; s > 0; s >>= 1) {
        if (t < s) sh[t] += sh[t + s];
        __syncthreads();
    }
    float r = sh[0]; __syncthreads();
    return r;
}

__device__ __forceinline__ float block_reduce_max(float v, float* sh) {
    int t = threadIdx.x;
    sh[t] = v; __syncthreads();
    for (int s = blockDim.x / 2; s > 0; s >>= 1) {
        if (t < s) sh[t] = fmaxf(sh[t], sh[t + s]);
        __syncthreads();
    }
    float r = sh[0]; __syncthreads();
    return r;
}

// ---------------- kernels ----------------

__global__ void zero_acc(float* acc) {
    if (threadIdx.x < 4) acc[threadIdx.x] = 0.0f;
}

// Gather rows from bert_emb; write tanh'd relation_hidden (B,2304) and raw toks_in (B,4,768)
__global__ __launch_bounds__(256) void gather_kernel(
    const float* __restrict__ bert, const int* __restrict__ eidx,
    float* __restrict__ rh, float* __restrict__ toks_in)
{
    int b = blockIdx.x;
    int t = threadIdx.x;
    int e00 = eidx[b*4 + 0];
    int e01 = eidx[b*4 + 1];
    int e10 = eidx[b*4 + 2];
    int e11 = eidx[b*4 + 3];
    const float* s0 = bert + (size_t)b * NS_ * S_ * H_;          // ns=0
    const float* s1 = s0 + (size_t)S_ * H_;                      // ns=1
    const float* cls  = s0;                                      // s=0
    const float* head = s0 + (size_t)e00 * H_;
    const float* tail = s0 + (size_t)e01 * H_;
    const float* h2a  = s1 + (size_t)e10 * H_;
    const float* h2b  = s1 + (size_t)e11 * H_;
    float* rhb = rh + (size_t)b * H3_;
    float* tk  = toks_in + (size_t)b * 4 * H_;
    for (int h = t; h < H_; h += 256) {
        float c  = cls[h];
        float hd = head[h];
        float tl = tail[h];
        rhb[h]          = tanhf(c);
        rhb[H_ + h]     = tanhf(hd);
        rhb[2*H_ + h]   = tanhf(tl);
        tk[h]           = hd;
        tk[H_ + h]      = tl;
        tk[2*H_ + h]    = h2a[h];
        tk[3*H_ + h]    = h2b[h];
    }
}

// Tiled GEMM: C = A(M,K) @ W(K,N) + bias, optional tanh.  M,N mult of 64, K mult of 16.
#define BM 64
#define BN 64
#define BK 16
__global__ __launch_bounds__(256) void gemm_ab(
    const float* __restrict__ A, const float* __restrict__ W,
    const float* __restrict__ bias, float* __restrict__ C,
    int M, int N, int K, int fuse_tanh)
{
    __shared__ float Ast[BK][BM + 4];   // [kk][r]
    __shared__ float Ws[BK][BN];        // [kk][c]
    int tid = threadIdx.x;
    int tx = tid & 15, ty = tid >> 4;
    int rowBase = blockIdx.y * BM;
    int colBase = blockIdx.x * BN;
    float acc[4][4] = {{0}};

    int ar = tid >> 2;             // 0..63
    int ak = (tid & 3) * 4;        // 0,4,8,12
    int wk = tid >> 4;             // 0..15
    int wc = (tid & 15) * 4;       // 0..60

    for (int k0 = 0; k0 < K; k0 += BK) {
        float4 av = *(const float4*)(A + (size_t)(rowBase + ar) * K + k0 + ak);
        float4 wv = *(const float4*)(W + (size_t)(k0 + wk) * N + colBase + wc);
        Ast[ak+0][ar] = av.x; Ast[ak+1][ar] = av.y;
        Ast[ak+2][ar] = av.z; Ast[ak+3][ar] = av.w;
        *(float4*)&Ws[wk][wc] = wv;
        __syncthreads();
#pragma unroll
        for (int kk = 0; kk < BK; ++kk) {
            float4 a = *(const float4*)&Ast[kk][ty*4];
            float4 w = *(const float4*)&Ws[kk][tx*4];
            acc[0][0] += a.x*w.x; acc[0][1] += a.x*w.y; acc[0][2] += a.x*w.z; acc[0][3] += a.x*w.w;
            acc[1][0] += a.y*w.x; acc[1][1] += a.y*w.y; acc[1][2] += a.y*w.z; acc[1][3] += a.y*w.w;
            acc[2][0] += a.z*w.x; acc[2][1] += a.z*w.y; acc[2][2] += a.z*w.z; acc[2][3] += a.z*w.w;
            acc[3][0] += a.w*w.x; acc[3][1] += a.w*w.y; acc[3][2] += a.w*w.z; acc[3][3] += a.w*w.w;
        }
        __syncthreads();
    }
    int col = colBase + tx * 4;
    float4 b4 = *(const float4*)(bias + col);
#pragma unroll
    for (int i = 0; i < 4; ++i) {
        int row = rowBase + ty * 4 + i;
        float4 o;
        o.x = acc[i][0] + b4.x; o.y = acc[i][1] + b4.y;
        o.z = acc[i][2] + b4.z; o.w = acc[i][3] + b4.w;
        if (fuse_tanh) { o.x = tanhf(o.x); o.y = tanhf(o.y); o.z = tanhf(o.z); o.w = tanhf(o.w); }
        *(float4*)(C + (size_t)row * N + col) = o;
    }
}

// Tiled GEMM: C(M,N) = scale * A(M,K; lda) @ B(N,K; ldb)^T.  M,N mult of 64, K mult of 16.
__global__ __launch_bounds__(256) void gemm_abt(
    const float* __restrict__ A, const float* __restrict__ Bp,
    float* __restrict__ C, int M, int N, int K, int lda, int ldb, float scale)
{
    __shared__ float Ast[BK][BM + 4];
    __shared__ float Bst[BK][BN + 4];
    int tid = threadIdx.x;
    int tx = tid & 15, ty = tid >> 4;
    int rowBase = blockIdx.y * BM;
    int colBase = blockIdx.x * BN;
    float acc[4][4] = {{0}};

    int ar = tid >> 2;
    int ak = (tid & 3) * 4;

    for (int k0 = 0; k0 < K; k0 += BK) {
        float4 av = *(const float4*)(A  + (size_t)(rowBase + ar) * lda + k0 + ak);
        float4 bv = *(const float4*)(Bp + (size_t)(colBase + ar) * ldb + k0 + ak);
        Ast[ak+0][ar] = av.x; Ast[ak+1][ar] = av.y;
        Ast[ak+2][ar] = av.z; Ast[ak+3][ar] = av.w;
        Bst[ak+0][ar] = bv.x; Bst[ak+1][ar] = bv.y;
        Bst[ak+2][ar] = bv.z; Bst[ak+3][ar] = bv.w;
        __syncthreads();
#pragma unroll
        for (int kk = 0; kk < BK; ++kk) {
            float4 a = *(const float4*)&Ast[kk][ty*4];
            float4 w = *(const float4*)&Bst[kk][tx*4];
            acc[0][0] += a.x*w.x; acc[0][1] += a.x*w.y; acc[0][2] += a.x*w.z; acc[0][3] += a.x*w.w;
            acc[1][0] += a.y*w.x; acc[1][1] += a.y*w.y; acc[1][2] += a.y*w.z; acc[1][3] += a.y*w.w;
            acc[2][0] += a.z*w.x; acc[2][1] += a.z*w.y; acc[2][2] += a.z*w.z; acc[2][3] += a.z*w.w;
            acc[3][0] += a.w*w.x; acc[3][1] += a.w*w.y; acc[3][2] += a.w*w.z; acc[3][3] += a.w*w.w;
        }
        __syncthreads();
    }
#pragma unroll
    for (int i = 0; i < 4; ++i) {
        int row = rowBase + ty * 4 + i;
        int col = colBase + tx * 4;
        float4 o;
        o.x = acc[i][0] * scale; o.y = acc[i][1] * scale;
        o.z = acc[i][2] * scale; o.w = acc[i][3] * scale;
        *(float4*)(C + (size_t)row * N + col) = o;
    }
}

// Row L2-normalize: out[r] = in[r] / max(||in[r]||, EPS). In-place safe.
__global__ __launch_bounds__(256) void norm_rows(
    const float* __restrict__ in, float* __restrict__ out, int D)
{
    __shared__ float sh[256];
    int r = blockIdx.x, t = threadIdx.x;
    const float* x = in + (size_t)r * D;
    float ss = 0.0f;
    for (int d = t; d < D; d += 256) { float v = x[d]; ss += v * v; }
    ss = block_reduce_sum(ss, sh);
    float inv = 1.0f / fmaxf(sqrtf(ss), EPS_);
    float* o = out + (size_t)r * D;
    for (int d = t; d < D; d += 256) o[d] = x[d] * inv;
}

// Fused: logits row (40) from rh(512,2304)@cls_w(2304,40)+b, then CE vs label. 1 wave/row.
__global__ __launch_bounds__(64) void cls_ce(
    const float* __restrict__ rh, const float* __restrict__ cls_w,
    const float* __restrict__ cls_b, const int* __restrict__ labels,
    float* __restrict__ acc)
{
    int i = blockIdx.x;
    int lane = threadIdx.x;
    float logit = -INFINITY;
    if (lane < NL_) {
        const float* r = rh + (size_t)i * H3_;
        float s0 = 0.f, s1 = 0.f, s2 = 0.f, s3 = 0.f;
        for (int k = 0; k < H3_; k += 4) {
            s0 += r[k+0] * cls_w[(k+0)*NL_ + lane];
            s1 += r[k+1] * cls_w[(k+1)*NL_ + lane];
            s2 += r[k+2] * cls_w[(k+2)*NL_ + lane];
            s3 += r[k+3] * cls_w[(k+3)*NL_ + lane];
        }
        logit = cls_b[lane] + ((s0 + s1) + (s2 + s3));
    }
    float m = logit;
    for (int off = 32; off >= 1; off >>= 1) m = fmaxf(m, __shfl_down(m, off));
    m = __shfl(m, 0);
    float e = (lane < NL_) ? expf(logit - m) : 0.0f;
    for (int off = 32; off >= 1; off >>= 1) e += __shfl_down(e, off);
    float se = __shfl(e, 0);
    int lbl = labels[i];
    float lt = __shfl(logit, lbl);
    if (lane == 0) atomicAdd(acc + 0, (logf(se) + m - lt) * (1.0f / (float)B_));
}

// Per-row margin from C1 (512x512): neg = max over diff-label cols clamped at 0;
// term = relu(neg - pos + GAMMA); accumulate raw sum into acc[1].
__global__ __launch_bounds__(256) void margin_row(
    const float* __restrict__ C1, const int* __restrict__ labels, float* __restrict__ acc)
{
    __shared__ float sh[256];
    int i = blockIdx.x, t = threadIdx.x;
    int li = labels[i];
    const float* row = C1 + (size_t)i * B_;
    float m = -INFINITY;
    for (int j = t; j < B_; j += 256)
        if (labels[j] != li) m = fmaxf(m, row[j]);
    float negmax = block_reduce_max(m, sh);
    if (t == 0) {
        float neg = fmaxf(negmax, 0.0f);
        float term = neg - row[i] + GAMMA_;
        if (term > 0.0f) atomicAdd(acc + 1, term);
    }
}

// Per-row CE of cos_sim (already scaled by 1/TEMP) with target=row index; mean into acc[2].
__global__ __launch_bounds__(256) void cosce_row(
    const float* __restrict__ C2, float* __restrict__ acc)
{
    __shared__ float sh[256];
    int i = blockIdx.x, t = threadIdx.x;
    const float* row = C2 + (size_t)i * B_;
    float m = -INFINITY;
    for (int j = t; j < B_; j += 256) m = fmaxf(m, row[j]);
    m = block_reduce_max(m, sh);
    float s = 0.0f;
    for (int j = t; j < B_; j += 256) s += expf(row[j] - m);
    s = block_reduce_sum(s, sh);
    if (t == 0) {
        float ce = logf(s) + m - row[i];
        atomicAdd(acc + 2, ce * (1.0f / (float)B_));
    }
}

__global__ void finalize(const float* __restrict__ acc, float* __restrict__ out) {
    if (threadIdx.x == 0 && blockIdx.x == 0)
        out[0] = acc[0] + (1.0f - ALPHA_) * acc[1] + ALPHA_ * acc[2];
}

// ---------------- launch ----------------

extern "C" void kernel_launch(void* const* d_in, const int* in_sizes, int n_in,
                              void* d_out, int out_size, void* d_ws, size_t ws_size,
                              hipStream_t stream) {
    const float* bert     = (const float*)d_in[0];
    const float* desc     = (const float*)d_in[1];
    const float* dense_w  = (const float*)d_in[2];
    const float* dense_b  = (const float*)d_in[3];
    const float* cls_w    = (const float*)d_in[4];
    const float* cls_b    = (const float*)d_in[5];
    const float* fc_w     = (const float*)d_in[6];
    const float* fc_b     = (const float*)d_in[7];
    const int*   eidx     = (const int*)d_in[8];
    const int*   labels   = (const int*)d_in[9];
    float* out = (float*)d_out;

    // workspace layout (floats)
    float* ws = (float*)d_ws;
    float* rh       = ws;                      // 512*2304   = 1,179,648
    float* toks_in  = rh + (size_t)B_*H3_;     // 512*4*768  = 1,572,864
    float* toks_out = toks_in + (size_t)B_*4*H_;   // 1,572,864
    float* desc_n   = toks_out + (size_t)B_*4*H_;  // 512*384
    float* rel_emb  = desc_n + (size_t)B_*DS_;     // 512*384
    float* C1       = rel_emb + (size_t)B_*DS_;    // 512*512
    float* C2       = C1 + (size_t)B_*B_;          // 512*512
    float* acc      = C2 + (size_t)B_*B_;          // 4

    zero_acc<<<1, 64, 0, stream>>>(acc);

    gather_kernel<<<B_, 256, 0, stream>>>(bert, eidx, rh, toks_in);

    // dense: toks_out(2048,768) = tanh(toks_in(2048,768) @ dense_w(768,768) + b)
    gemm_ab<<<dim3(H_/BN, (B_*4)/BM), 256, 0, stream>>>(
        toks_in, dense_w, dense_b, toks_out, B_*4, H_, H_, 1);

    // fc: rel_emb(512,384) = rh(512,2304) @ fc_w(2304,384) + b
    gemm_ab<<<dim3(DS_/BN, B_/BM), 256, 0, stream>>>(
        rh, fc_w, fc_b, rel_emb, B_, DS_, H3_, 0);

    // classification CE (needs rh only)
    cls_ce<<<B_, 64, 0, stream>>>(rh, cls_w, cls_b, labels, acc);

    // normalizations
    norm_rows<<<B_, 256, 0, stream>>>(desc, desc_n, DS_);
    norm_rows<<<B_, 256, 0, stream>>>(rel_emb, rel_emb, DS_);
    norm_rows<<<B_*2, 256, 0, stream>>>(toks_out, toks_out, 2*H_);  // (1024,1536) rows

    // C1 = rel_n @ desc_n^T  (512,512), K=384
    gemm_abt<<<dim3(B_/BN, B_/BM), 256, 0, stream>>>(
        rel_emb, desc_n, C1, B_, B_, DS_, DS_, DS_, 1.0f);
    margin_row<<<B_, 256, 0, stream>>>(C1, labels, acc);

    // C2 = z1n @ z2n^T / TEMP  (512,512), K=1536, row stride 3072
    gemm_abt<<<dim3(B_/BN, B_/BM), 256, 0, stream>>>(
        toks_out, toks_out + 2*H_, C2, B_, B_, 2*H_, 4*H_, 4*H_, 1.0f / TEMP_);
    cosce_row<<<B_, 256, 0, stream>>>(C2, acc);

    finalize<<<1, 64, 0, stream>>>(acc, out);
}

// Round 2
// 723.532 us; speedup vs baseline: 1.2751x; 1.2751x over previous
//
#include <hip/hip_runtime.h>
#include <hip/hip_bf16.h>
#include <math.h>

// Problem constants
#define B_   512
#define NS_  2
#define S_   128
#define H_   768
#define DS_  384
#define NL_  40
#define H3_  (3*H_)      // 2304
#define TEMP_ 0.05f
#define ALPHA_ 0.15f
#define GAMMA_ 7.5f
#define EPS_ 1e-8f

typedef __attribute__((ext_vector_type(8))) short bf8_t;
typedef __attribute__((ext_vector_type(4))) float f4_t;

// ---------------- helpers ----------------

__device__ __forceinline__ float block_reduce_sum(float v, float* sh) {
    int t = threadIdx.x;
    sh[t] = v; __syncthreads();
    for (int s = blockDim.x / 2; s > 0; s >>= 1) {
        if (t < s) sh[t] += sh[t + s];
        __syncthreads();
    }
    float r = sh[0]; __syncthreads();
    return r;
}

__device__ __forceinline__ float block_reduce_max(float v, float* sh) {
    int t = threadIdx.x;
    sh[t] = v; __syncthreads();
    for (int s = blockDim.x / 2; s > 0; s >>= 1) {
        if (t < s) sh[t] = fmaxf(sh[t], sh[t + s]);
        __syncthreads();
    }
    float r = sh[0]; __syncthreads();
    return r;
}

// ---------------- kernels ----------------

// Gather rows from bert_emb; write bf16 tanh'd relation_hidden (B,2304) and bf16 toks_in (B,4,768).
// Block 0 also zeroes the 4 accumulators.
__global__ __launch_bounds__(256) void gather_kernel(
    const float* __restrict__ bert, const int* __restrict__ eidx,
    __hip_bfloat16* __restrict__ rh_bf, __hip_bfloat16* __restrict__ toks_bf,
    float* __restrict__ acc)
{
    int b = blockIdx.x;
    int t = threadIdx.x;
    if (b == 0 && t < 4) acc[t] = 0.0f;
    int e00 = eidx[b*4 + 0];
    int e01 = eidx[b*4 + 1];
    int e10 = eidx[b*4 + 2];
    int e11 = eidx[b*4 + 3];
    const float* s0 = bert + (size_t)b * NS_ * S_ * H_;
    const float* s1 = s0 + (size_t)S_ * H_;
    const float* cls  = s0;
    const float* head = s0 + (size_t)e00 * H_;
    const float* tail = s0 + (size_t)e01 * H_;
    const float* h2a  = s1 + (size_t)e10 * H_;
    const float* h2b  = s1 + (size_t)e11 * H_;
    __hip_bfloat16* rhb = rh_bf + (size_t)b * H3_;
    __hip_bfloat16* tk  = toks_bf + (size_t)b * 4 * H_;
    for (int h = t; h < H_; h += 256) {
        float c  = cls[h];
        float hd = head[h];
        float tl = tail[h];
        rhb[h]        = __float2bfloat16(tanhf(c));
        rhb[H_ + h]   = __float2bfloat16(tanhf(hd));
        rhb[2*H_ + h] = __float2bfloat16(tanhf(tl));
        tk[h]         = __float2bfloat16(hd);
        tk[H_ + h]    = __float2bfloat16(tl);
        tk[2*H_ + h]  = __float2bfloat16(h2a[h]);
        tk[3*H_ + h]  = __float2bfloat16(h2b[h]);
    }
}

// Transpose + convert: out[n][k] = bf16(in[k][n]); in is (K,N).
__global__ __launch_bounds__(256) void transpose_bf(
    const float* __restrict__ in, __hip_bfloat16* __restrict__ out, int K, int N)
{
    __shared__ float tile[32][33];
    int n0 = blockIdx.x * 32, k0 = blockIdx.y * 32;
    int tx = threadIdx.x, ty = threadIdx.y;   // block (32,8)
#pragma unroll
    for (int i = 0; i < 4; ++i) {
        int k = k0 + ty + i*8, n = n0 + tx;
        if (k < K && n < N) tile[ty + i*8][tx] = in[(size_t)k * N + n];
    }
    __syncthreads();
#pragma unroll
    for (int i = 0; i < 4; ++i) {
        int n = n0 + ty + i*8, k = k0 + tx;
        if (n < N && k < K) out[(size_t)n * K + k] = __float2bfloat16(tile[tx][ty + i*8]);
    }
}

// MFMA GEMM: C(M,N) fp32 = scale * A(M,K,lda)_bf16 @ B(N,K,ldb)_bf16^T [+bias] [tanh]
// Block tile 128x128, 4 waves in 2x2 of 64x64, K-step 32, 16x16x32 bf16 MFMA.
// Requires: M % 128 == 0, K % 32 == 0. N guarded.
#define LDSPAD 40   // row stride in bf16 elems (32 + 8 pad); 80B, 16B-aligned
__global__ __launch_bounds__(256) void mfma_abt(
    const __hip_bfloat16* __restrict__ A, const __hip_bfloat16* __restrict__ Bp,
    const float* __restrict__ bias, float* __restrict__ C,
    int M, int N, int K, int lda, int ldb, int ldc,
    float scale, int fuse_tanh, int has_bias)
{
    __shared__ __hip_bfloat16 As[128 * LDSPAD];
    __shared__ __hip_bfloat16 Bs[128 * LDSPAD];
    int tid  = threadIdx.x;
    int lane = tid & 63;
    int wave = tid >> 6;
    int wm = (wave >> 1) * 64;
    int wn = (wave & 1) * 64;
    int lr = lane & 15;
    int quad = lane >> 4;
    int rowBase = blockIdx.y * 128;
    int colBase = blockIdx.x * 128;

    f4_t acc[4][4];
#pragma unroll
    for (int i = 0; i < 4; ++i)
#pragma unroll
        for (int j = 0; j < 4; ++j) acc[i][j] = (f4_t){0.f, 0.f, 0.f, 0.f};

    for (int k0 = 0; k0 < K; k0 += 32) {
        // stage A and B tiles: 128 rows x 32 k (4 chunks of 8 bf16 = 16B)
#pragma unroll
        for (int half = 0; half < 2; ++half) {
            int chunk = tid + half * 256;
            int r = chunk >> 2, c = chunk & 3;
            // A
            {
                bf8_t v = *(const bf8_t*)(A + (size_t)(rowBase + r) * lda + k0 + c * 8);
                *(bf8_t*)&As[r * LDSPAD + c * 8] = v;
            }
            // B (N-guarded)
            {
                bf8_t v;
                if (colBase + r < N)
                    v = *(const bf8_t*)(Bp + (size_t)(colBase + r) * ldb + k0 + c * 8);
                else
                    v = (bf8_t){0,0,0,0,0,0,0,0};
                *(bf8_t*)&Bs[r * LDSPAD + c * 8] = v;
            }
        }
        __syncthreads();
        bf8_t af[4], bfr[4];
#pragma unroll
        for (int f = 0; f < 4; ++f) {
            af[f]  = *(const bf8_t*)&As[(wm + f*16 + lr) * LDSPAD + quad * 8];
            bfr[f] = *(const bf8_t*)&Bs[(wn + f*16 + lr) * LDSPAD + quad * 8];
        }
#pragma unroll
        for (int i = 0; i < 4; ++i)
#pragma unroll
            for (int j = 0; j < 4; ++j)
                acc[i][j] = __builtin_amdgcn_mfma_f32_16x16x32_bf16(af[i], bfr[j], acc[i][j], 0, 0, 0);
        __syncthreads();
    }

    // epilogue: C/D layout col=lane&15, row=quad*4+reg
#pragma unroll
    for (int j = 0; j < 4; ++j) {
        int col = colBase + wn + j*16 + lr;
        if (col >= N) continue;
        float bv = has_bias ? bias[col] : 0.0f;
#pragma unroll
        for (int i = 0; i < 4; ++i) {
            int row0 = rowBase + wm + i*16 + quad*4;
#pragma unroll
            for (int r = 0; r < 4; ++r) {
                float v = acc[i][j][r] * scale + bv;
                if (fuse_tanh) v = tanhf(v);
                C[(size_t)(row0 + r) * ldc + col] = v;
            }
        }
    }
}

// Row L2-normalize fp32 in -> bf16 out.
__global__ __launch_bounds__(256) void norm_rows_bf(
    const float* __restrict__ in, __hip_bfloat16* __restrict__ out, int D)
{
    __shared__ float sh[256];
    int r = blockIdx.x, t = threadIdx.x;
    const float* x = in + (size_t)r * D;
    float ss = 0.0f;
    for (int d = t; d < D; d += 256) { float v = x[d]; ss += v * v; }
    ss = block_reduce_sum(ss, sh);
    float inv = 1.0f / fmaxf(sqrtf(ss), EPS_);
    __hip_bfloat16* o = out + (size_t)r * D;
    for (int d = t; d < D; d += 256) o[d] = __float2bfloat16(x[d] * inv);
}

// CE over precomputed logits (512 x 40, ld=40), mean into acc[0]. One wave per row.
__global__ __launch_bounds__(64) void ce_logits(
    const float* __restrict__ logits, const int* __restrict__ labels, float* __restrict__ acc)
{
    int i = blockIdx.x;
    int lane = threadIdx.x;
    float logit = (lane < NL_) ? logits[(size_t)i * NL_ + lane] : -INFINITY;
    float m = logit;
    for (int off = 32; off >= 1; off >>= 1) m = fmaxf(m, __shfl_down(m, off));
    m = __shfl(m, 0);
    float e = (lane < NL_) ? expf(logit - m) : 0.0f;
    for (int off = 32; off >= 1; off >>= 1) e += __shfl_down(e, off);
    float se = __shfl(e, 0);
    float lt = __shfl(logit, labels[i]);
    if (lane == 0) atomicAdd(acc + 0, (logf(se) + m - lt) * (1.0f / (float)B_));
}

// Per-row margin from C1 (512x512)
__global__ __launch_bounds__(256) void margin_row(
    const float* __restrict__ C1, const int* __restrict__ labels, float* __restrict__ acc)
{
    __shared__ float sh[256];
    int i = blockIdx.x, t = threadIdx.x;
    int li = labels[i];
    const float* row = C1 + (size_t)i * B_;
    float m = -INFINITY;
    for (int j = t; j < B_; j += 256)
        if (labels[j] != li) m = fmaxf(m, row[j]);
    float negmax = block_reduce_max(m, sh);
    if (t == 0) {
        float neg = fmaxf(negmax, 0.0f);
        float term = neg - row[i] + GAMMA_;
        if (term > 0.0f) atomicAdd(acc + 1, term);
    }
}

// Per-row CE of cos_sim with target=row index; mean into acc[2].
__global__ __launch_bounds__(256) void cosce_row(
    const float* __restrict__ C2, float* __restrict__ acc)
{
    __shared__ float sh[256];
    int i = blockIdx.x, t = threadIdx.x;
    const float* row = C2 + (size_t)i * B_;
    float m = -INFINITY;
    for (int j = t; j < B_; j += 256) m = fmaxf(m, row[j]);
    m = block_reduce_max(m, sh);
    float s = 0.0f;
    for (int j = t; j < B_; j += 256) s += expf(row[j] - m);
    s = block_reduce_sum(s, sh);
    if (t == 0) atomicAdd(acc + 2, (logf(s) + m - row[i]) * (1.0f / (float)B_));
}

__global__ void finalize(const float* __restrict__ acc, float* __restrict__ out) {
    if (threadIdx.x == 0 && blockIdx.x == 0)
        out[0] = acc[0] + (1.0f - ALPHA_) * acc[1] + ALPHA_ * acc[2];
}

// ---------------- launch ----------------

extern "C" void kernel_launch(void* const* d_in, const int* in_sizes, int n_in,
                              void* d_out, int out_size, void* d_ws, size_t ws_size,
                              hipStream_t stream) {
    const float* bert     = (const float*)d_in[0];
    const float* desc     = (const float*)d_in[1];
    const float* dense_w  = (const float*)d_in[2];
    const float* dense_b  = (const float*)d_in[3];
    const float* cls_w    = (const float*)d_in[4];
    const float* cls_b    = (const float*)d_in[5];
    const float* fc_w     = (const float*)d_in[6];
    const float* fc_b     = (const float*)d_in[7];
    const int*   eidx     = (const int*)d_in[8];
    const int*   labels   = (const int*)d_in[9];
    float* out = (float*)d_out;

    // workspace layout (in float units; bf16 buffers use 2 elems per float slot)
    float* ws = (float*)d_ws;
    float* fp = ws;
    __hip_bfloat16* rh_bf   = (__hip_bfloat16*)fp; fp += (size_t)B_*H3_/2;        // 512x2304 bf16
    __hip_bfloat16* toks_bf = (__hip_bfloat16*)fp; fp += (size_t)B_*4*H_/2;       // 2048x768 bf16
    __hip_bfloat16* dwt_bf  = (__hip_bfloat16*)fp; fp += (size_t)H_*H_/2;         // 768x768 bf16 (W^T)
    __hip_bfloat16* fwt_bf  = (__hip_bfloat16*)fp; fp += (size_t)DS_*H3_/2;       // 384x2304 bf16
    __hip_bfloat16* cwt_bf  = (__hip_bfloat16*)fp; fp += (size_t)NL_*H3_/2;       // 40x2304 bf16
    __hip_bfloat16* desc_nb = (__hip_bfloat16*)fp; fp += (size_t)B_*DS_/2;        // 512x384 bf16
    __hip_bfloat16* rel_nb  = (__hip_bfloat16*)fp; fp += (size_t)B_*DS_/2;        // 512x384 bf16
    __hip_bfloat16* z_bf    = (__hip_bfloat16*)fp; fp += (size_t)B_*4*H_/2;       // 1024x1536 bf16
    float* toks_out = fp; fp += (size_t)B_*4*H_;     // 2048x768 fp32
    float* rel_emb  = fp; fp += (size_t)B_*DS_;      // 512x384
    float* logits   = fp; fp += (size_t)B_*NL_;      // 512x40
    float* C1       = fp; fp += (size_t)B_*B_;       // 512x512
    float* C2       = fp; fp += (size_t)B_*B_;       // 512x512
    float* acc      = fp;                            // 4

    // gather (+ zero acc)
    gather_kernel<<<B_, 256, 0, stream>>>(bert, eidx, rh_bf, toks_bf, acc);

    // weight transposes -> bf16
    transpose_bf<<<dim3((H_+31)/32, (H_+31)/32), dim3(32,8), 0, stream>>>(dense_w, dwt_bf, H_, H_);
    transpose_bf<<<dim3((DS_+31)/32, (H3_+31)/32), dim3(32,8), 0, stream>>>(fc_w, fwt_bf, H3_, DS_);
    transpose_bf<<<dim3((NL_+31)/32, (H3_+31)/32), dim3(32,8), 0, stream>>>(cls_w, cwt_bf, H3_, NL_);

    // dense: toks_out(2048,768) = tanh(toks_bf @ dwt^T + dense_b)
    mfma_abt<<<dim3(H_/128, (B_*4)/128), 256, 0, stream>>>(
        toks_bf, dwt_bf, dense_b, toks_out, B_*4, H_, H_, H_, H_, H_, 1.0f, 1, 1);

    // fc: rel_emb(512,384) = rh @ fwt^T + fc_b
    mfma_abt<<<dim3(DS_/128, B_/128), 256, 0, stream>>>(
        rh_bf, fwt_bf, fc_b, rel_emb, B_, DS_, H3_, H3_, H3_, DS_, 1.0f, 0, 1);

    // cls logits: (512,40) = rh @ cwt^T + cls_b
    mfma_abt<<<dim3(1, B_/128), 256, 0, stream>>>(
        rh_bf, cwt_bf, cls_b, logits, B_, NL_, H3_, H3_, H3_, NL_, 1.0f, 0, 1);
    ce_logits<<<B_, 64, 0, stream>>>(logits, labels, acc);

    // normalizations (fp32 reduce, bf16 out)
    norm_rows_bf<<<B_, 256, 0, stream>>>(desc, desc_nb, DS_);
    norm_rows_bf<<<B_, 256, 0, stream>>>(rel_emb, rel_nb, DS_);
    norm_rows_bf<<<B_*2, 256, 0, stream>>>(toks_out, z_bf, 2*H_);   // (1024,1536) contiguous rows

    // C1 = rel_n @ desc_n^T (512,512), K=384
    mfma_abt<<<dim3(B_/128, B_/128), 256, 0, stream>>>(
        rel_nb, desc_nb, (const float*)nullptr, C1, B_, B_, DS_, DS_, DS_, B_, 1.0f, 0, 0);
    margin_row<<<B_, 256, 0, stream>>>(C1, labels, acc);

    // C2 = z1n @ z2n^T / TEMP (512,512), K=1536; z rows at stride 3072
    mfma_abt<<<dim3(B_/128, B_/128), 256, 0, stream>>>(
        z_bf, z_bf + 2*H_, (const float*)nullptr, C2, B_, B_, 2*H_, 4*H_, 4*H_, B_, 1.0f/TEMP_, 0, 0);
    cosce_row<<<B_, 256, 0, stream>>>(C2, acc);

    finalize<<<1, 64, 0, stream>>>(acc, out);
}

// Round 3
// 600.535 us; speedup vs baseline: 1.5362x; 1.2048x over previous
//
#include <hip/hip_runtime.h>
#include <hip/hip_bf16.h>
#include <math.h>

// Problem constants
#define B_   512
#define NS_  2
#define S_   128
#define H_   768
#define DS_  384
#define NL_  40
#define H3_  (3*H_)      // 2304
#define TEMP_ 0.05f
#define ALPHA_ 0.15f
#define GAMMA_ 7.5f
#define EPS_ 1e-8f

typedef __attribute__((ext_vector_type(8))) short bf8_t;
typedef __attribute__((ext_vector_type(4))) float f4_t;

#define LDSPAD 40   // bf16 row stride for 32-wide k tiles (80B, 16B-aligned)

// ---------------- helpers ----------------

__device__ __forceinline__ float block_reduce_sum(float v, float* sh) {
    int t = threadIdx.x;
    sh[t] = v; __syncthreads();
    for (int s = blockDim.x / 2; s > 0; s >>= 1) {
        if (t < s) sh[t] += sh[t + s];
        __syncthreads();
    }
    float r = sh[0]; __syncthreads();
    return r;
}

__device__ __forceinline__ float block_reduce_max(float v, float* sh) {
    int t = threadIdx.x;
    sh[t] = v; __syncthreads();
    for (int s = blockDim.x / 2; s > 0; s >>= 1) {
        if (t < s) sh[t] = fmaxf(sh[t], sh[t + s]);
        __syncthreads();
    }
    float r = sh[0]; __syncthreads();
    return r;
}

// ---------------- prep: gather + 3 weight transposes, one launch ----------------
// blocks [0,512): gather batch b (also block 0 zeroes acc)
// blocks [512,1088):  transpose dense_w (768x768)  -> dwt (768x768)
// blocks [1088,1952): transpose fc_w   (2304x384)  -> fwt (384x2304)
// blocks [1952,2096): transpose cls_w  (2304x40)   -> cwt (40x2304)
__device__ __forceinline__ void transpose_tile(
    const float* __restrict__ in, __hip_bfloat16* __restrict__ out,
    int K, int N, int kt, int nt, int tid, float* tileLds /* 32*33 */)
{
    int k0 = kt * 32, n0 = nt * 32;
    int tx = tid & 31, ty = tid >> 5;   // ty 0..7
#pragma unroll
    for (int i = 0; i < 4; ++i) {
        int k = k0 + ty + i * 8, n = n0 + tx;
        if (k < K && n < N) tileLds[(ty + i*8) * 33 + tx] = in[(size_t)k * N + n];
    }
    __syncthreads();
#pragma unroll
    for (int i = 0; i < 4; ++i) {
        int n = n0 + ty + i * 8, k = k0 + tx;
        if (n < N && k < K) out[(size_t)n * K + k] = __float2bfloat16(tileLds[tx * 33 + ty + i*8]);
    }
}

__global__ __launch_bounds__(256) void prep_kernel(
    const float* __restrict__ bert, const int* __restrict__ eidx,
    const float* __restrict__ dense_w, const float* __restrict__ fc_w,
    const float* __restrict__ cls_w,
    __hip_bfloat16* __restrict__ rh_bf, __hip_bfloat16* __restrict__ toks_bf,
    __hip_bfloat16* __restrict__ dwt, __hip_bfloat16* __restrict__ fwt,
    __hip_bfloat16* __restrict__ cwt, float* __restrict__ acc)
{
    __shared__ float tileLds[32 * 33];
    int blk = blockIdx.x;
    int t = threadIdx.x;
    if (blk < 512) {
        int b = blk;
        if (b == 0 && t < 4) acc[t] = 0.0f;
        int e00 = eidx[b*4 + 0];
        int e01 = eidx[b*4 + 1];
        int e10 = eidx[b*4 + 2];
        int e11 = eidx[b*4 + 3];
        const float* s0 = bert + (size_t)b * NS_ * S_ * H_;
        const float* s1 = s0 + (size_t)S_ * H_;
        const float* cls  = s0;
        const float* head = s0 + (size_t)e00 * H_;
        const float* tail = s0 + (size_t)e01 * H_;
        const float* h2a  = s1 + (size_t)e10 * H_;
        const float* h2b  = s1 + (size_t)e11 * H_;
        __hip_bfloat16* rhb = rh_bf + (size_t)b * H3_;
        __hip_bfloat16* tk  = toks_bf + (size_t)b * 4 * H_;
        for (int h = t; h < H_; h += 256) {
            float c  = cls[h];
            float hd = head[h];
            float tl = tail[h];
            rhb[h]        = __float2bfloat16(tanhf(c));
            rhb[H_ + h]   = __float2bfloat16(tanhf(hd));
            rhb[2*H_ + h] = __float2bfloat16(tanhf(tl));
            tk[h]         = __float2bfloat16(hd);
            tk[H_ + h]    = __float2bfloat16(tl);
            tk[2*H_ + h]  = __float2bfloat16(h2a[h]);
            tk[3*H_ + h]  = __float2bfloat16(h2b[h]);
        }
    } else if (blk < 1088) {
        int q = blk - 512;          // 24x24 tiles
        transpose_tile(dense_w, dwt, H_, H_, q / 24, q % 24, t, tileLds);
    } else if (blk < 1952) {
        int q = blk - 1088;         // 72x12 tiles
        transpose_tile(fc_w, fwt, H3_, DS_, q / 12, q % 12, t, tileLds);
    } else {
        int q = blk - 1952;         // 72x2 tiles
        transpose_tile(cls_w, cwt, H3_, NL_, q / 2, q % 2, t, tileLds);
    }
}

// ---------------- MFMA GEMM, 128x128 tile (dense only) ----------------
// C(M,N) fp32 = tanh?(A(M,K,lda)_bf16 @ B(N,K,ldb)_bf16^T + bias)
__global__ __launch_bounds__(256) void mfma_abt128(
    const __hip_bfloat16* __restrict__ A, const __hip_bfloat16* __restrict__ Bp,
    const float* __restrict__ bias, float* __restrict__ C,
    int K, int lda, int ldb, int ldc, int fuse_tanh)
{
    __shared__ __hip_bfloat16 As[128 * LDSPAD];
    __shared__ __hip_bfloat16 Bs[128 * LDSPAD];
    int tid  = threadIdx.x;
    int lane = tid & 63;
    int wave = tid >> 6;
    int wm = (wave >> 1) * 64;
    int wn = (wave & 1) * 64;
    int lr = lane & 15;
    int quad = lane >> 4;
    int rowBase = blockIdx.y * 128;
    int colBase = blockIdx.x * 128;

    f4_t acc[4][4];
#pragma unroll
    for (int i = 0; i < 4; ++i)
#pragma unroll
        for (int j = 0; j < 4; ++j) acc[i][j] = (f4_t){0.f, 0.f, 0.f, 0.f};

    int sr = tid >> 2, sc = tid & 3;
    for (int k0 = 0; k0 < K; k0 += 32) {
#pragma unroll
        for (int half = 0; half < 2; ++half) {
            int r = sr + half * 64;
            *(bf8_t*)&As[r * LDSPAD + sc * 8] =
                *(const bf8_t*)(A + (size_t)(rowBase + r) * lda + k0 + sc * 8);
            *(bf8_t*)&Bs[r * LDSPAD + sc * 8] =
                *(const bf8_t*)(Bp + (size_t)(colBase + r) * ldb + k0 + sc * 8);
        }
        __syncthreads();
        bf8_t af[4], bfr[4];
#pragma unroll
        for (int f = 0; f < 4; ++f) {
            af[f]  = *(const bf8_t*)&As[(wm + f*16 + lr) * LDSPAD + quad * 8];
            bfr[f] = *(const bf8_t*)&Bs[(wn + f*16 + lr) * LDSPAD + quad * 8];
        }
#pragma unroll
        for (int i = 0; i < 4; ++i)
#pragma unroll
            for (int j = 0; j < 4; ++j)
                acc[i][j] = __builtin_amdgcn_mfma_f32_16x16x32_bf16(af[i], bfr[j], acc[i][j], 0, 0, 0);
        __syncthreads();
    }
#pragma unroll
    for (int j = 0; j < 4; ++j) {
        int col = colBase + wn + j*16 + lr;
        float bv = bias ? bias[col] : 0.0f;
#pragma unroll
        for (int i = 0; i < 4; ++i) {
            int row0 = rowBase + wm + i*16 + quad*4;
#pragma unroll
            for (int r = 0; r < 4; ++r) {
                float v = acc[i][j][r] + bv;
                if (fuse_tanh) v = tanhf(v);
                C[(size_t)(row0 + r) * ldc + col] = v;
            }
        }
    }
}

// ---------------- MFMA GEMM, 64x64 tile (fc, C1, C2) ----------------
// Wave w computes cols [w*16,w*16+16) x all 64 rows. M,N mult of 64, K mult of 32.
__global__ __launch_bounds__(256) void mfma_abt64(
    const __hip_bfloat16* __restrict__ A, const __hip_bfloat16* __restrict__ Bp,
    const float* __restrict__ bias, float* __restrict__ C,
    int K, int lda, int ldb, int ldc, float scale)
{
    __shared__ __hip_bfloat16 As[64 * LDSPAD];
    __shared__ __hip_bfloat16 Bs[64 * LDSPAD];
    int tid  = threadIdx.x;
    int lane = tid & 63;
    int wave = tid >> 6;
    int lr = lane & 15;
    int quad = lane >> 4;
    int rowBase = blockIdx.y * 64;
    int colBase = blockIdx.x * 64;

    f4_t acc[4];
#pragma unroll
    for (int i = 0; i < 4; ++i) acc[i] = (f4_t){0.f, 0.f, 0.f, 0.f};

    int sr = tid >> 2, sc = tid & 3;   // 64 rows x 4 chunks
    for (int k0 = 0; k0 < K; k0 += 32) {
        *(bf8_t*)&As[sr * LDSPAD + sc * 8] =
            *(const bf8_t*)(A + (size_t)(rowBase + sr) * lda + k0 + sc * 8);
        *(bf8_t*)&Bs[sr * LDSPAD + sc * 8] =
            *(const bf8_t*)(Bp + (size_t)(colBase + sr) * ldb + k0 + sc * 8);
        __syncthreads();
        bf8_t bfr = *(const bf8_t*)&Bs[(wave*16 + lr) * LDSPAD + quad * 8];
#pragma unroll
        for (int f = 0; f < 4; ++f) {
            bf8_t af = *(const bf8_t*)&As[(f*16 + lr) * LDSPAD + quad * 8];
            acc[f] = __builtin_amdgcn_mfma_f32_16x16x32_bf16(af, bfr, acc[f], 0, 0, 0);
        }
        __syncthreads();
    }
    int col = colBase + wave*16 + lr;
    float bv = bias ? bias[col] : 0.0f;
#pragma unroll
    for (int f = 0; f < 4; ++f) {
        int row0 = rowBase + f*16 + quad*4;
#pragma unroll
        for (int r = 0; r < 4; ++r)
            C[(size_t)(row0 + r) * ldc + col] = acc[f][r] * scale + bv;
    }
}

// ---------------- cls logits GEMM + CE, fully fused ----------------
// grid 8 blocks x 64 rows. N=40 padded to 48. Logits stay in LDS.
__global__ __launch_bounds__(256) void cls_ce_fused(
    const __hip_bfloat16* __restrict__ rh, const __hip_bfloat16* __restrict__ cwt,
    const float* __restrict__ cls_b, const int* __restrict__ labels,
    float* __restrict__ acc)
{
    __shared__ __hip_bfloat16 As[64 * LDSPAD];
    __shared__ __hip_bfloat16 Bs[48 * LDSPAD];
    __shared__ float lg[64 * 48];
    __shared__ float shred[64];
    int tid  = threadIdx.x;
    int lane = tid & 63;
    int wave = tid >> 6;
    int lr = lane & 15;
    int quad = lane >> 4;
    int rowBase = blockIdx.x * 64;

    f4_t a3[3];
#pragma unroll
    for (int j = 0; j < 3; ++j) a3[j] = (f4_t){0.f, 0.f, 0.f, 0.f};

    int sr = tid >> 2, sc = tid & 3;
    for (int k0 = 0; k0 < H3_; k0 += 32) {
        *(bf8_t*)&As[sr * LDSPAD + sc * 8] =
            *(const bf8_t*)(rh + (size_t)(rowBase + sr) * H3_ + k0 + sc * 8);
        if (tid < 192) {
            bf8_t v = (sr < NL_) ? *(const bf8_t*)(cwt + (size_t)sr * H3_ + k0 + sc * 8)
                                 : (bf8_t){0,0,0,0,0,0,0,0};
            *(bf8_t*)&Bs[sr * LDSPAD + sc * 8] = v;
        }
        __syncthreads();
        bf8_t af = *(const bf8_t*)&As[(wave*16 + lr) * LDSPAD + quad * 8];
#pragma unroll
        for (int j = 0; j < 3; ++j) {
            bf8_t bfr = *(const bf8_t*)&Bs[(j*16 + lr) * LDSPAD + quad * 8];
            a3[j] = __builtin_amdgcn_mfma_f32_16x16x32_bf16(af, bfr, a3[j], 0, 0, 0);
        }
        __syncthreads();
    }
    // dump logits (+bias) to LDS; wave w owns rows [w*16, w*16+16)
#pragma unroll
    for (int j = 0; j < 3; ++j) {
        int col = j*16 + lr;
        float bv = (col < NL_) ? cls_b[col] : 0.0f;
#pragma unroll
        for (int r = 0; r < 4; ++r) {
            int rowl = wave*16 + quad*4 + r;
            lg[rowl * 48 + col] = (col < NL_) ? (a3[j][r] + bv) : -INFINITY;
        }
    }
    __syncthreads();
    if (tid < 64) {
        const float* Lr = &lg[tid * 48];
        float m = -INFINITY;
        for (int c = 0; c < NL_; ++c) m = fmaxf(m, Lr[c]);
        float s = 0.0f;
        for (int c = 0; c < NL_; ++c) s += expf(Lr[c] - m);
        int lbl = labels[rowBase + tid];
        shred[tid] = logf(s) + m - Lr[lbl];
    }
    __syncthreads();
    if (tid < 32) shred[tid] += shred[tid + 32];
    __syncthreads();
    if (tid < 16) shred[tid] += shred[tid + 16];
    __syncthreads();
    if (tid < 8) shred[tid] += shred[tid + 8];
    __syncthreads();
    if (tid == 0) {
        float s = 0.0f;
        for (int i = 0; i < 8; ++i) s += shred[i];
        atomicAdd(acc + 0, s * (1.0f / (float)B_));
    }
}

// ---------------- norms: desc (512) + rel (512) + z (1024), one launch ----------------
__global__ __launch_bounds__(256) void norms_kernel(
    const float* __restrict__ desc, const float* __restrict__ rel_emb,
    const float* __restrict__ toks_out,
    __hip_bfloat16* __restrict__ desc_nb, __hip_bfloat16* __restrict__ rel_nb,
    __hip_bfloat16* __restrict__ z_bf)
{
    __shared__ float sh[256];
    int blk = blockIdx.x, t = threadIdx.x;
    const float* x; __hip_bfloat16* o; int D;
    if (blk < 512)       { x = desc + (size_t)blk * DS_;            o = desc_nb + (size_t)blk * DS_;            D = DS_; }
    else if (blk < 1024) { x = rel_emb + (size_t)(blk-512) * DS_;   o = rel_nb + (size_t)(blk-512) * DS_;       D = DS_; }
    else                 { x = toks_out + (size_t)(blk-1024)*2*H_;  o = z_bf + (size_t)(blk-1024)*2*H_;         D = 2*H_; }
    float ss = 0.0f;
    for (int d = t; d < D; d += 256) { float v = x[d]; ss += v * v; }
    ss = block_reduce_sum(ss, sh);
    float inv = 1.0f / fmaxf(sqrtf(ss), EPS_);
    for (int d = t; d < D; d += 256) o[d] = __float2bfloat16(x[d] * inv);
}

// ---------------- margin (512 rows of C1) + cos-CE (512 rows of C2), one launch ----------------
__global__ __launch_bounds__(256) void tail_kernel(
    const float* __restrict__ C1, const float* __restrict__ C2,
    const int* __restrict__ labels, float* __restrict__ acc)
{
    __shared__ float sh[256];
    int blk = blockIdx.x, t = threadIdx.x;
    if (blk < 512) {
        int i = blk;
        int li = labels[i];
        const float* row = C1 + (size_t)i * B_;
        float m = -INFINITY;
        for (int j = t; j < B_; j += 256)
            if (labels[j] != li) m = fmaxf(m, row[j]);
        float negmax = block_reduce_max(m, sh);
        if (t == 0) {
            float neg = fmaxf(negmax, 0.0f);
            float term = neg - row[i] + GAMMA_;
            if (term > 0.0f) atomicAdd(acc + 1, term);
        }
    } else {
        int i = blk - 512;
        const float* row = C2 + (size_t)i * B_;
        float m = -INFINITY;
        for (int j = t; j < B_; j += 256) m = fmaxf(m, row[j]);
        m = block_reduce_max(m, sh);
        float s = 0.0f;
        for (int j = t; j < B_; j += 256) s += expf(row[j] - m);
        s = block_reduce_sum(s, sh);
        if (t == 0) atomicAdd(acc + 2, (logf(s) + m - row[i]) * (1.0f / (float)B_));
    }
}

__global__ void finalize(const float* __restrict__ acc, float* __restrict__ out) {
    if (threadIdx.x == 0 && blockIdx.x == 0)
        out[0] = acc[0] + (1.0f - ALPHA_) * acc[1] + ALPHA_ * acc[2];
}

// ---------------- launch ----------------

extern "C" void kernel_launch(void* const* d_in, const int* in_sizes, int n_in,
                              void* d_out, int out_size, void* d_ws, size_t ws_size,
                              hipStream_t stream) {
    const float* bert     = (const float*)d_in[0];
    const float* desc     = (const float*)d_in[1];
    const float* dense_w  = (const float*)d_in[2];
    const float* dense_b  = (const float*)d_in[3];
    const float* cls_w    = (const float*)d_in[4];
    const float* cls_b    = (const float*)d_in[5];
    const float* fc_w     = (const float*)d_in[6];
    const float* fc_b     = (const float*)d_in[7];
    const int*   eidx     = (const int*)d_in[8];
    const int*   labels   = (const int*)d_in[9];
    float* out = (float*)d_out;

    float* fp = (float*)d_ws;
    __hip_bfloat16* rh_bf   = (__hip_bfloat16*)fp; fp += (size_t)B_*H3_/2;
    __hip_bfloat16* toks_bf = (__hip_bfloat16*)fp; fp += (size_t)B_*4*H_/2;
    __hip_bfloat16* dwt_bf  = (__hip_bfloat16*)fp; fp += (size_t)H_*H_/2;
    __hip_bfloat16* fwt_bf  = (__hip_bfloat16*)fp; fp += (size_t)DS_*H3_/2;
    __hip_bfloat16* cwt_bf  = (__hip_bfloat16*)fp; fp += (size_t)NL_*H3_/2;
    __hip_bfloat16* desc_nb = (__hip_bfloat16*)fp; fp += (size_t)B_*DS_/2;
    __hip_bfloat16* rel_nb  = (__hip_bfloat16*)fp; fp += (size_t)B_*DS_/2;
    __hip_bfloat16* z_bf    = (__hip_bfloat16*)fp; fp += (size_t)B_*4*H_/2;
    float* toks_out = fp; fp += (size_t)B_*4*H_;
    float* rel_emb  = fp; fp += (size_t)B_*DS_;
    float* C1       = fp; fp += (size_t)B_*B_;
    float* C2       = fp; fp += (size_t)B_*B_;
    float* acc      = fp;

    // 1. prep: gather + transposes (+ zero acc)
    prep_kernel<<<2096, 256, 0, stream>>>(bert, eidx, dense_w, fc_w, cls_w,
                                          rh_bf, toks_bf, dwt_bf, fwt_bf, cwt_bf, acc);

    // 2. dense: toks_out(2048,768) = tanh(toks_bf @ dwt^T + dense_b)
    mfma_abt128<<<dim3(H_/128, (B_*4)/128), 256, 0, stream>>>(
        toks_bf, dwt_bf, dense_b, toks_out, H_, H_, H_, H_, 1);

    // 3. fc: rel_emb(512,384) = rh @ fwt^T + fc_b
    mfma_abt64<<<dim3(DS_/64, B_/64), 256, 0, stream>>>(
        rh_bf, fwt_bf, fc_b, rel_emb, H3_, H3_, H3_, DS_, 1.0f);

    // 4. cls logits + CE (one kernel, logits in LDS)
    cls_ce_fused<<<B_/64, 256, 0, stream>>>(rh_bf, cwt_bf, cls_b, labels, acc);

    // 5. all normalizations
    norms_kernel<<<2048, 256, 0, stream>>>(desc, rel_emb, toks_out, desc_nb, rel_nb, z_bf);

    // 6. C1 = rel_n @ desc_n^T (512,512), K=384
    mfma_abt64<<<dim3(B_/64, B_/64), 256, 0, stream>>>(
        rel_nb, desc_nb, (const float*)nullptr, C1, DS_, DS_, DS_, B_, 1.0f);

    // 7. C2 = z1n @ z2n^T / TEMP (512,512), K=1536, row stride 3072
    mfma_abt64<<<dim3(B_/64, B_/64), 256, 0, stream>>>(
        z_bf, z_bf + 2*H_, (const float*)nullptr, C2, 2*H_, 4*H_, 4*H_, B_, 1.0f/TEMP_);

    // 8. margin + cos-CE
    tail_kernel<<<1024, 256, 0, stream>>>(C1, C2, labels, acc);

    // 9. combine
    finalize<<<1, 64, 0, stream>>>(acc, out);
}

// Round 4
// 569.885 us; speedup vs baseline: 1.6188x; 1.0538x over previous
//
#include <hip/hip_runtime.h>
#include <hip/hip_bf16.h>
#include <math.h>

// Problem constants
#define B_   512
#define NS_  2
#define S_   128
#define H_   768
#define DS_  384
#define NL_  40
#define H3_  (3*H_)      // 2304
#define TEMP_ 0.05f
#define ALPHA_ 0.15f
#define GAMMA_ 7.5f
#define EPS_ 1e-8f

typedef __attribute__((ext_vector_type(8))) short bf8_t;
typedef __attribute__((ext_vector_type(4))) float f4_t;

#define LDSPAD 40   // bf16 row stride for 32-wide k tiles (80B, 16B-aligned)

// ---------------- helpers ----------------

__device__ __forceinline__ float block_reduce_sum(float v, float* sh) {
    int t = threadIdx.x;
    sh[t] = v; __syncthreads();
    for (int s = blockDim.x / 2; s > 0; s >>= 1) {
        if (t < s) sh[t] += sh[t + s];
        __syncthreads();
    }
    float r = sh[0]; __syncthreads();
    return r;
}

__device__ __forceinline__ float block_reduce_max(float v, float* sh) {
    int t = threadIdx.x;
    sh[t] = v; __syncthreads();
    for (int s = blockDim.x / 2; s > 0; s >>= 1) {
        if (t < s) sh[t] = fmaxf(sh[t], sh[t + s]);
        __syncthreads();
    }
    float r = sh[0]; __syncthreads();
    return r;
}

// ---------------- kernel 1: prep ----------------
// blocks [0,512): gather batch b (block 0 also zeroes acc + done)
// blocks [512,1088):  transpose dense_w (768x768)  -> dwt (768x768)
// blocks [1088,1952): transpose fc_w   (2304x384)  -> fwt (384x2304)
// blocks [1952,2096): transpose cls_w  (2304x40)   -> cwt (48x2304, rows 40..47 zeroed)
// blocks [2096,2608): desc row L2-norm -> desc_nb
__device__ __forceinline__ void transpose_tile(
    const float* __restrict__ in, __hip_bfloat16* __restrict__ out,
    int K, int N, int kt, int nt, int tid, float* tileLds /* 32*33 */)
{
    int k0 = kt * 32, n0 = nt * 32;
    int tx = tid & 31, ty = tid >> 5;   // ty 0..7
#pragma unroll
    for (int i = 0; i < 4; ++i) {
        int k = k0 + ty + i * 8, n = n0 + tx;
        if (k < K && n < N) tileLds[(ty + i*8) * 33 + tx] = in[(size_t)k * N + n];
    }
    __syncthreads();
#pragma unroll
    for (int i = 0; i < 4; ++i) {
        int n = n0 + ty + i * 8, k = k0 + tx;
        if (n < N && k < K) out[(size_t)n * K + k] = __float2bfloat16(tileLds[tx * 33 + ty + i*8]);
    }
}

__global__ __launch_bounds__(256) void prep_kernel(
    const float* __restrict__ bert, const int* __restrict__ eidx,
    const float* __restrict__ dense_w, const float* __restrict__ fc_w,
    const float* __restrict__ cls_w, const float* __restrict__ desc,
    __hip_bfloat16* __restrict__ rh_bf, __hip_bfloat16* __restrict__ toks_bf,
    __hip_bfloat16* __restrict__ dwt, __hip_bfloat16* __restrict__ fwt,
    __hip_bfloat16* __restrict__ cwt, __hip_bfloat16* __restrict__ desc_nb,
    float* __restrict__ acc, int* __restrict__ done)
{
    __shared__ float tileLds[32 * 33];
    int blk = blockIdx.x;
    int t = threadIdx.x;
    if (blk < 512) {
        int b = blk;
        if (b == 0) {
            if (t < 4) acc[t] = 0.0f;
            if (t == 4) *done = 0;
        }
        int e00 = eidx[b*4 + 0];
        int e01 = eidx[b*4 + 1];
        int e10 = eidx[b*4 + 2];
        int e11 = eidx[b*4 + 3];
        const float* s0 = bert + (size_t)b * NS_ * S_ * H_;
        const float* s1 = s0 + (size_t)S_ * H_;
        const float* cls  = s0;
        const float* head = s0 + (size_t)e00 * H_;
        const float* tail = s0 + (size_t)e01 * H_;
        const float* h2a  = s1 + (size_t)e10 * H_;
        const float* h2b  = s1 + (size_t)e11 * H_;
        __hip_bfloat16* rhb = rh_bf + (size_t)b * H3_;
        __hip_bfloat16* tk  = toks_bf + (size_t)b * 4 * H_;
        for (int h = t; h < H_; h += 256) {
            float c  = cls[h];
            float hd = head[h];
            float tl = tail[h];
            rhb[h]        = __float2bfloat16(tanhf(c));
            rhb[H_ + h]   = __float2bfloat16(tanhf(hd));
            rhb[2*H_ + h] = __float2bfloat16(tanhf(tl));
            tk[h]         = __float2bfloat16(hd);
            tk[H_ + h]    = __float2bfloat16(tl);
            tk[2*H_ + h]  = __float2bfloat16(h2a[h]);
            tk[3*H_ + h]  = __float2bfloat16(h2b[h]);
        }
    } else if (blk < 1088) {
        int q = blk - 512;          // 24x24 tiles
        transpose_tile(dense_w, dwt, H_, H_, q / 24, q % 24, t, tileLds);
    } else if (blk < 1952) {
        int q = blk - 1088;         // 72x12 tiles
        transpose_tile(fc_w, fwt, H3_, DS_, q / 12, q % 12, t, tileLds);
    } else if (blk < 2096) {
        int q = blk - 1952;         // 72x2 tiles
        int kt = q / 2, nt = q % 2;
        transpose_tile(cls_w, cwt, H3_, NL_, kt, nt, t, tileLds);
        if (nt == 1) {              // zero pad rows 40..47 for this k-range
            int tx = t & 31, ty = t >> 5;
            cwt[(size_t)(40 + ty) * H3_ + kt * 32 + tx] = __float2bfloat16(0.0f);
        }
    } else {
        int i = blk - 2096;         // desc norm, D=384
        const float* x = desc + (size_t)i * DS_;
        float ss = 0.0f;
        for (int d = t; d < DS_; d += 256) { float v = x[d]; ss += v * v; }
        ss = block_reduce_sum(ss, tileLds);
        float inv = 1.0f / fmaxf(sqrtf(ss), EPS_);
        __hip_bfloat16* o = desc_nb + (size_t)i * DS_;
        for (int d = t; d < DS_; d += 256) o[d] = __float2bfloat16(x[d] * inv);
    }
}

// ---------------- GEMM device bodies (shared smem) ----------------

// 128x128 tile MFMA: C = tanh?(A@B^T + bias)
__device__ __forceinline__ void gemm128_body(
    const __hip_bfloat16* __restrict__ A, const __hip_bfloat16* __restrict__ Bp,
    const float* __restrict__ bias, float* __restrict__ C,
    int K, int lda, int ldb, int ldc, int fuse_tanh, int bx, int by,
    __hip_bfloat16* As, __hip_bfloat16* Bs)
{
    int tid  = threadIdx.x;
    int lane = tid & 63;
    int wave = tid >> 6;
    int wm = (wave >> 1) * 64;
    int wn = (wave & 1) * 64;
    int lr = lane & 15;
    int quad = lane >> 4;
    int rowBase = by * 128;
    int colBase = bx * 128;

    f4_t acc[4][4];
#pragma unroll
    for (int i = 0; i < 4; ++i)
#pragma unroll
        for (int j = 0; j < 4; ++j) acc[i][j] = (f4_t){0.f, 0.f, 0.f, 0.f};

    int sr = tid >> 2, sc = tid & 3;
    for (int k0 = 0; k0 < K; k0 += 32) {
#pragma unroll
        for (int half = 0; half < 2; ++half) {
            int r = sr + half * 64;
            *(bf8_t*)&As[r * LDSPAD + sc * 8] =
                *(const bf8_t*)(A + (size_t)(rowBase + r) * lda + k0 + sc * 8);
            *(bf8_t*)&Bs[r * LDSPAD + sc * 8] =
                *(const bf8_t*)(Bp + (size_t)(colBase + r) * ldb + k0 + sc * 8);
        }
        __syncthreads();
        bf8_t af[4], bfr[4];
#pragma unroll
        for (int f = 0; f < 4; ++f) {
            af[f]  = *(const bf8_t*)&As[(wm + f*16 + lr) * LDSPAD + quad * 8];
            bfr[f] = *(const bf8_t*)&Bs[(wn + f*16 + lr) * LDSPAD + quad * 8];
        }
#pragma unroll
        for (int i = 0; i < 4; ++i)
#pragma unroll
            for (int j = 0; j < 4; ++j)
                acc[i][j] = __builtin_amdgcn_mfma_f32_16x16x32_bf16(af[i], bfr[j], acc[i][j], 0, 0, 0);
        __syncthreads();
    }
#pragma unroll
    for (int j = 0; j < 4; ++j) {
        int col = colBase + wn + j*16 + lr;
        float bv = bias ? bias[col] : 0.0f;
#pragma unroll
        for (int i = 0; i < 4; ++i) {
            int row0 = rowBase + wm + i*16 + quad*4;
#pragma unroll
            for (int r = 0; r < 4; ++r) {
                float v = acc[i][j][r] + bv;
                if (fuse_tanh) v = tanhf(v);
                C[(size_t)(row0 + r) * ldc + col] = v;
            }
        }
    }
}

// 64x64 tile MFMA: C = scale*(A@B^T) + bias
__device__ __forceinline__ void gemm64_body(
    const __hip_bfloat16* __restrict__ A, const __hip_bfloat16* __restrict__ Bp,
    const float* __restrict__ bias, float* __restrict__ C,
    int K, int lda, int ldb, int ldc, float scale, int bx, int by,
    __hip_bfloat16* As, __hip_bfloat16* Bs)
{
    int tid  = threadIdx.x;
    int lane = tid & 63;
    int wave = tid >> 6;
    int lr = lane & 15;
    int quad = lane >> 4;
    int rowBase = by * 64;
    int colBase = bx * 64;

    f4_t acc[4];
#pragma unroll
    for (int i = 0; i < 4; ++i) acc[i] = (f4_t){0.f, 0.f, 0.f, 0.f};

    int sr = tid >> 2, sc = tid & 3;
    for (int k0 = 0; k0 < K; k0 += 32) {
        *(bf8_t*)&As[sr * LDSPAD + sc * 8] =
            *(const bf8_t*)(A + (size_t)(rowBase + sr) * lda + k0 + sc * 8);
        *(bf8_t*)&Bs[sr * LDSPAD + sc * 8] =
            *(const bf8_t*)(Bp + (size_t)(colBase + sr) * ldb + k0 + sc * 8);
        __syncthreads();
        bf8_t bfr = *(const bf8_t*)&Bs[(wave*16 + lr) * LDSPAD + quad * 8];
#pragma unroll
        for (int f = 0; f < 4; ++f) {
            bf8_t af = *(const bf8_t*)&As[(f*16 + lr) * LDSPAD + quad * 8];
            acc[f] = __builtin_amdgcn_mfma_f32_16x16x32_bf16(af, bfr, acc[f], 0, 0, 0);
        }
        __syncthreads();
    }
    int col = colBase + wave*16 + lr;
    float bv = bias ? bias[col] : 0.0f;
#pragma unroll
    for (int f = 0; f < 4; ++f) {
        int row0 = rowBase + f*16 + quad*4;
#pragma unroll
        for (int r = 0; r < 4; ++r)
            C[(size_t)(row0 + r) * ldc + col] = acc[f][r] * scale + bv;
    }
}

// cls logits + CE, 16 rows/block, K split across 4 waves, no LDS staging.
__device__ __forceinline__ void cls_ce_body(
    const __hip_bfloat16* __restrict__ rh, const __hip_bfloat16* __restrict__ cwt,
    const float* __restrict__ cls_b, const int* __restrict__ labels,
    float* __restrict__ acc, int rowBase, float* lgp /* 4*16*48 floats */)
{
    int tid  = threadIdx.x;
    int lane = tid & 63;
    int wave = tid >> 6;
    int lr = lane & 15;
    int quad = lane >> 4;

    f4_t a3[3];
#pragma unroll
    for (int j = 0; j < 3; ++j) a3[j] = (f4_t){0.f, 0.f, 0.f, 0.f};

    int kw0 = wave * (H3_ / 4);    // 576 per wave
    const __hip_bfloat16* aRow = rh + (size_t)(rowBase + lr) * H3_ + quad * 8;
#pragma unroll 2
    for (int s = 0; s < 18; ++s) {
        int k = kw0 + s * 32;
        bf8_t af = *(const bf8_t*)(aRow + k);
#pragma unroll
        for (int j = 0; j < 3; ++j) {
            bf8_t bfr = *(const bf8_t*)(cwt + (size_t)(j*16 + lr) * H3_ + k + quad * 8);
            a3[j] = __builtin_amdgcn_mfma_f32_16x16x32_bf16(af, bfr, a3[j], 0, 0, 0);
        }
    }
    // partials -> LDS: lgp[w*768 + row*48 + col]
#pragma unroll
    for (int j = 0; j < 3; ++j) {
        int col = j*16 + lr;
#pragma unroll
        for (int r = 0; r < 4; ++r)
            lgp[wave * 768 + (quad*4 + r) * 48 + col] = a3[j][r];
    }
    __syncthreads();
    // combine 4 partials + bias
    for (int idx = tid; idx < 768; idx += 256) {
        int col = idx % 48;
        float s = lgp[idx] + lgp[768 + idx] + lgp[1536 + idx] + lgp[2304 + idx];
        s = (col < NL_) ? (s + cls_b[col]) : -INFINITY;
        lgp[idx] = s;
    }
    __syncthreads();
    if (tid < 64) {
        float ce = 0.0f;
        if (tid < 16) {
            const float* Lr = &lgp[tid * 48];
            float m = -INFINITY;
            for (int c = 0; c < NL_; ++c) m = fmaxf(m, Lr[c]);
            float s = 0.0f;
            for (int c = 0; c < NL_; ++c) s += expf(Lr[c] - m);
            ce = logf(s) + m - Lr[labels[rowBase + tid]];
        }
        for (int off = 8; off >= 1; off >>= 1) ce += __shfl_down(ce, off);
        if (tid == 0) atomicAdd(acc + 0, ce * (1.0f / (float)B_));
    }
}

// ---------------- kernel 2: dense(96) + fc(48) + cls_ce(32) ----------------
__global__ __launch_bounds__(256) void gemms_kernel(
    const __hip_bfloat16* __restrict__ toks_bf, const __hip_bfloat16* __restrict__ dwt,
    const float* __restrict__ dense_b, float* __restrict__ toks_out,
    const __hip_bfloat16* __restrict__ rh_bf, const __hip_bfloat16* __restrict__ fwt,
    const float* __restrict__ fc_b, float* __restrict__ rel_emb,
    const __hip_bfloat16* __restrict__ cwt, const float* __restrict__ cls_b,
    const int* __restrict__ labels, float* __restrict__ acc)
{
    __shared__ __align__(16) char smem[2 * 128 * LDSPAD * 2];   // 20480 B
    int blk = blockIdx.x;
    if (blk < 96) {
        gemm128_body(toks_bf, dwt, dense_b, toks_out, H_, H_, H_, H_, 1,
                     blk % 6, blk / 6,
                     (__hip_bfloat16*)smem, (__hip_bfloat16*)(smem + 128 * LDSPAD * 2));
    } else if (blk < 144) {
        int q = blk - 96;
        gemm64_body(rh_bf, fwt, fc_b, rel_emb, H3_, H3_, H3_, DS_, 1.0f,
                    q % 6, q / 6,
                    (__hip_bfloat16*)smem, (__hip_bfloat16*)(smem + 64 * LDSPAD * 2));
    } else {
        cls_ce_body(rh_bf, cwt, cls_b, labels, acc, (blk - 144) * 16, (float*)smem);
    }
}

// ---------------- kernel 3: rel norm (512) + z norm (1024) ----------------
__global__ __launch_bounds__(256) void znorm_kernel(
    const float* __restrict__ rel_emb, const float* __restrict__ toks_out,
    __hip_bfloat16* __restrict__ rel_nb, __hip_bfloat16* __restrict__ z_bf)
{
    __shared__ float sh[256];
    int blk = blockIdx.x, t = threadIdx.x;
    const float* x; __hip_bfloat16* o; int D;
    if (blk < 512) { x = rel_emb + (size_t)blk * DS_;          o = rel_nb + (size_t)blk * DS_;        D = DS_; }
    else           { x = toks_out + (size_t)(blk-512) * 2*H_;  o = z_bf + (size_t)(blk-512) * 2*H_;   D = 2*H_; }
    float ss = 0.0f;
    for (int d = t; d < D; d += 256) { float v = x[d]; ss += v * v; }
    ss = block_reduce_sum(ss, sh);
    float inv = 1.0f / fmaxf(sqrtf(ss), EPS_);
    for (int d = t; d < D; d += 256) o[d] = __float2bfloat16(x[d] * inv);
}

// ---------------- kernel 4: C1 (64 blocks) + C2 (64 blocks) ----------------
__global__ __launch_bounds__(256) void c1c2_kernel(
    const __hip_bfloat16* __restrict__ rel_nb, const __hip_bfloat16* __restrict__ desc_nb,
    const __hip_bfloat16* __restrict__ z_bf, float* __restrict__ C1, float* __restrict__ C2)
{
    __shared__ __align__(16) char smem[2 * 64 * LDSPAD * 2];
    __hip_bfloat16* As = (__hip_bfloat16*)smem;
    __hip_bfloat16* Bs = (__hip_bfloat16*)(smem + 64 * LDSPAD * 2);
    int blk = blockIdx.x;
    if (blk < 64) {
        gemm64_body(rel_nb, desc_nb, (const float*)nullptr, C1, DS_, DS_, DS_, B_, 1.0f,
                    blk % 8, blk / 8, As, Bs);
    } else {
        int q = blk - 64;
        gemm64_body(z_bf, z_bf + 2*H_, (const float*)nullptr, C2, 2*H_, 4*H_, 4*H_, B_, 1.0f/TEMP_,
                    q % 8, q / 8, As, Bs);
    }
}

// ---------------- kernel 5: margin (512) + cos-CE (512) + last-block finalize ----------------
__global__ __launch_bounds__(256) void tail_kernel(
    const float* __restrict__ C1, const float* __restrict__ C2,
    const int* __restrict__ labels, float* __restrict__ acc,
    int* __restrict__ done, float* __restrict__ out)
{
    __shared__ float sh[256];
    int blk = blockIdx.x, t = threadIdx.x;
    if (blk < 512) {
        int i = blk;
        int li = labels[i];
        const float* row = C1 + (size_t)i * B_;
        float m = -INFINITY;
        for (int j = t; j < B_; j += 256)
            if (labels[j] != li) m = fmaxf(m, row[j]);
        float negmax = block_reduce_max(m, sh);
        if (t == 0) {
            float neg = fmaxf(negmax, 0.0f);
            float term = neg - row[i] + GAMMA_;
            if (term > 0.0f) atomicAdd(acc + 1, term);
        }
    } else {
        int i = blk - 512;
        const float* row = C2 + (size_t)i * B_;
        float m = -INFINITY;
        for (int j = t; j < B_; j += 256) m = fmaxf(m, row[j]);
        m = block_reduce_max(m, sh);
        float s = 0.0f;
        for (int j = t; j < B_; j += 256) s += expf(row[j] - m);
        s = block_reduce_sum(s, sh);
        if (t == 0) atomicAdd(acc + 2, (logf(s) + m - row[i]) * (1.0f / (float)B_));
    }
    __threadfence();
    if (t == 0) {
        int prev = atomicAdd(done, 1);
        if (prev == 1023) {
            float a0 = atomicAdd(acc + 0, 0.0f);
            float a1 = atomicAdd(acc + 1, 0.0f);
            float a2 = atomicAdd(acc + 2, 0.0f);
            out[0] = a0 + (1.0f - ALPHA_) * a1 + ALPHA_ * a2;
        }
    }
}

// ---------------- launch ----------------

extern "C" void kernel_launch(void* const* d_in, const int* in_sizes, int n_in,
                              void* d_out, int out_size, void* d_ws, size_t ws_size,
                              hipStream_t stream) {
    const float* bert     = (const float*)d_in[0];
    const float* desc     = (const float*)d_in[1];
    const float* dense_w  = (const float*)d_in[2];
    const float* dense_b  = (const float*)d_in[3];
    const float* cls_w    = (const float*)d_in[4];
    const float* cls_b    = (const float*)d_in[5];
    const float* fc_w     = (const float*)d_in[6];
    const float* fc_b     = (const float*)d_in[7];
    const int*   eidx     = (const int*)d_in[8];
    const int*   labels   = (const int*)d_in[9];
    float* out = (float*)d_out;

    float* fp = (float*)d_ws;
    __hip_bfloat16* rh_bf   = (__hip_bfloat16*)fp; fp += (size_t)B_*H3_/2;
    __hip_bfloat16* toks_bf = (__hip_bfloat16*)fp; fp += (size_t)B_*4*H_/2;
    __hip_bfloat16* dwt_bf  = (__hip_bfloat16*)fp; fp += (size_t)H_*H_/2;
    __hip_bfloat16* fwt_bf  = (__hip_bfloat16*)fp; fp += (size_t)DS_*H3_/2;
    __hip_bfloat16* cwt_bf  = (__hip_bfloat16*)fp; fp += (size_t)48*H3_/2;   // padded to 48 rows
    __hip_bfloat16* desc_nb = (__hip_bfloat16*)fp; fp += (size_t)B_*DS_/2;
    __hip_bfloat16* rel_nb  = (__hip_bfloat16*)fp; fp += (size_t)B_*DS_/2;
    __hip_bfloat16* z_bf    = (__hip_bfloat16*)fp; fp += (size_t)B_*4*H_/2;
    float* toks_out = fp; fp += (size_t)B_*4*H_;
    float* rel_emb  = fp; fp += (size_t)B_*DS_;
    float* C1       = fp; fp += (size_t)B_*B_;
    float* C2       = fp; fp += (size_t)B_*B_;
    float* acc      = fp; fp += 4;
    int*   done     = (int*)fp;

    // 1. prep: gather + transposes + desc norm (+ zero acc/done)
    prep_kernel<<<2608, 256, 0, stream>>>(bert, eidx, dense_w, fc_w, cls_w, desc,
                                          rh_bf, toks_bf, dwt_bf, fwt_bf, cwt_bf,
                                          desc_nb, acc, done);

    // 2. dense + fc + cls_ce (independent, one launch)
    gemms_kernel<<<176, 256, 0, stream>>>(toks_bf, dwt_bf, dense_b, toks_out,
                                          rh_bf, fwt_bf, fc_b, rel_emb,
                                          cwt_bf, cls_b, labels, acc);

    // 3. rel + z norms
    znorm_kernel<<<1536, 256, 0, stream>>>(rel_emb, toks_out, rel_nb, z_bf);

    // 4. C1 + C2
    c1c2_kernel<<<128, 256, 0, stream>>>(rel_nb, desc_nb, z_bf, C1, C2);

    // 5. margin + cos-CE + finalize (last block writes out)
    tail_kernel<<<1024, 256, 0, stream>>>(C1, C2, labels, acc, done, out);
}